// Round 8
// baseline (448.735 us; speedup 1.0000x reference)
//
#include <hip/hip_runtime.h>

typedef unsigned short ushort_t;
typedef unsigned int uint_t;
typedef __attribute__((ext_vector_type(8))) short short8;
typedef __attribute__((ext_vector_type(4))) float float4v;
typedef __attribute__((ext_vector_type(4))) uint_t uint4v;

#define NLAT 2048
#define DLAT 64

// d_ws layout (ushort units): [0..127] flag area (int at byte 0), then packed weights
#define PW_BASE 128
#define PW0_OFF 0        // layer0: KT=7 -> 7*16*64*8 = 57344 ushorts
#define PW1_OFF 57344    // KT=8 -> 65536 each
#define PW2_OFF 122880
#define PW3_OFF 188416

__device__ __forceinline__ float b2f(ushort_t u) {
  union { uint_t i; float f; } v; v.i = ((uint_t)u) << 16; return v.f;
}
__device__ __forceinline__ ushort_t f2b(float f) {
  uint_t x = __float_as_uint(f);
  uint_t r = (x + 0x7fffu + ((x >> 16) & 1u)) >> 16;   // RNE
  return (ushort_t)r;
}
__device__ __forceinline__ uint_t pack2(float lo, float hi) {
  return (uint_t)f2b(lo) | ((uint_t)f2b(hi) << 16);
}
__device__ __forceinline__ int imin(int a, int b) { return a < b ? a : b; }
__device__ __forceinline__ int imax(int a, int b) { return a > b ? a : b; }

__device__ __forceinline__ float ldv(const float* p, long i)    { return p[i]; }
__device__ __forceinline__ float ldv(const ushort_t* p, long i) { return b2f(p[i]); }
__device__ __forceinline__ void stv(float* p, long i, float v)    { p[i] = v; }
__device__ __forceinline__ void stv(ushort_t* p, long i, float v) { p[i] = f2b(v); }

__device__ __forceinline__ float4 load4f(const float* p) { return *(const float4*)p; }
__device__ __forceinline__ float4 load4f(const ushort_t* p) {
  uint2 u = *(const uint2*)p;
  float4 r;
  r.x = b2f((ushort_t)(u.x & 0xffffu)); r.y = b2f((ushort_t)(u.x >> 16));
  r.z = b2f((ushort_t)(u.y & 0xffffu)); r.w = b2f((ushort_t)(u.y >> 16));
  return r;
}

// async 16B/lane global->LDS copy (gfx950 global_load_lds_dwordx4)
__device__ __forceinline__ void async_copy16(const ushort_t* g, ushort_t* l) {
  __builtin_amdgcn_global_load_lds(
      (const __attribute__((address_space(1))) void*)g,
      (__attribute__((address_space(3))) void*)l, 16, 0, 0);
}

// ---------------------------------------------------------------------------
// Stage weight chunk gi (global chunk index 0..31; layer gi>>3, c = gi&7,
// 2 mt-tiles = KT*2048 bytes) into a 16KB LDS buffer. 256 threads.
// ---------------------------------------------------------------------------
__device__ __forceinline__ void stage_idx(int gi, ushort_t* dst,
                                          const ushort_t* __restrict__ pw, int tid) {
  int layer = gi >> 3, c = gi & 7;
  int KT = (gi < 8) ? 7 : 8;
  int loff = (layer == 0) ? PW0_OFF : (layer == 1) ? PW1_OFF
           : (layer == 2) ? PW2_OFF : PW3_OFF;
  const ushort_t* src = pw + loff + c * KT * 1024;
  int n = KT * 128;                       // 16B issues
#pragma unroll
  for (int r = 0; r < 4; ++r) {
    int i = tid + (r << 8);
    if (i < n) async_copy16(src + (size_t)i * 8, dst + (size_t)i * 8);
  }
}

// ---------------------------------------------------------------------------
// Runtime dtype probe: flag=1 -> fp32 inputs, flag=0 -> bf16
// ---------------------------------------------------------------------------
__global__ void detect_mode(const ushort_t* __restrict__ lat, int* __restrict__ flag) {
  if (threadIdx.x == 0) *flag = 0;
  __syncthreads();
  int big = 0;
  for (int i = threadIdx.x; i < 1024; i += 64) {
    float v = b2f(lat[i]);
    if (!(fabsf(v) < 1e5f)) big = 1;
  }
  if (__any(big) && threadIdx.x == 0) *flag = 1;
}

// ---------------------------------------------------------------------------
// Pack weights as MFMA A-fragments (A = W^T, m = chan_out), sigma k-permuted
// to match the C-register order of the previous layer:
//   element j of frag(mt,kt,lane) = W[sigma][mt*16 + (lane&15)]
//   sigma = 32*kt + 16*(j>>2) + 4*(lane>>4) + (j&3)
// Layer 0: sigma indexes [sampled(192) | coord | pe(12) | pad->224].
// ---------------------------------------------------------------------------
template <typename TI>
__global__ void pack_w_t(const TI* __restrict__ W0, const TI* __restrict__ W1,
                         const TI* __restrict__ W2, const TI* __restrict__ W3,
                         ushort_t* __restrict__ pw, const int* __restrict__ flag, int want)
{
  if (*flag != want) return;
  int g = blockIdx.x * blockDim.x + threadIdx.x;
  if (g >= 31 * 1024) return;
  int lane = g & 63, q = lane >> 4;
  int mt   = (g >> 6) & 15;
  int ktg  = g >> 10;                       // 0..30
  const TI* W; ushort_t* dst; int kt, KT; bool isw0 = false;
  if (ktg < 7)       { W = W0; dst = pw + PW0_OFF; kt = ktg;      KT = 7; isw0 = true; }
  else if (ktg < 15) { W = W1; dst = pw + PW1_OFF; kt = ktg - 7;  KT = 8; }
  else if (ktg < 23) { W = W2; dst = pw + PW2_OFF; kt = ktg - 15; KT = 8; }
  else               { W = W3; dst = pw + PW3_OFF; kt = ktg - 23; KT = 8; }
  int col = mt * 16 + (lane & 15);
  uint_t words[4];
#pragma unroll
  for (int h = 0; h < 4; ++h) {
    ushort_t vv[2];
#pragma unroll
    for (int e = 0; e < 2; ++e) {
      int j = 2 * h + e;
      int f = 32 * kt + 16 * (j >> 2) + 4 * q + (j & 3);
      int row = f;
      if (isw0) row = (f < 192) ? (13 + f) : (f == 192 ? 0 : (f <= 204 ? f - 192 : -1));
      vv[e] = (row >= 0) ? f2b(ldv(W, (long)row * 256 + col)) : (ushort_t)0;
    }
    words[h] = (uint_t)vv[0] | ((uint_t)vv[1] << 16);
  }
  uint4 o; o.x = words[0]; o.y = words[1]; o.z = words[2]; o.w = words[3];
  *(uint4*)(dst + ((size_t)(mt * KT + kt) * 64 + lane) * 8) = o;
}

// ---------------------------------------------------------------------------
// One layer as 8 chunk-passes (2 mt-tiles per chunk). acc[2][2] only (16 regs).
// Chunk c converts directly into hout[c] (sigma order). LAST layer folds each
// chunk into the w4 dot instead.
// ---------------------------------------------------------------------------
template <int KT, int BASE, bool LAST>
__device__ __forceinline__ void layer_run(
    uint4v (&hin)[8][2], uint4v (&hout)[8][2],
    const float* bwl, const float* w4t,
    ushort_t (*wbuf)[8192], const ushort_t* __restrict__ pw,
    int tid, int lane, int q,
    float& partial0, float& partial1)
{
#pragma unroll
  for (int c = 0; c < 8; ++c) {
    constexpr int NB = 8;  // chunks per layer
    const int gi = BASE + c;
    if (gi + 1 < 32) stage_idx(gi + 1, wbuf[(gi + 1) & 1], pw, tid);
    const ushort_t* buf = wbuf[gi & 1];

    float4v acc[2][2];
#pragma unroll
    for (int m = 0; m < 2; ++m) {
      acc[m][0] = (float4v){0.f, 0.f, 0.f, 0.f};
      acc[m][1] = (float4v){0.f, 0.f, 0.f, 0.f};
    }
#pragma unroll
    for (int kt = 0; kt < KT; ++kt) {
      short8 b0 = __builtin_bit_cast(short8, hin[kt][0]);
      short8 b1 = __builtin_bit_cast(short8, hin[kt][1]);
#pragma unroll
      for (int m = 0; m < 2; ++m) {
        short8 a = *(const short8*)&buf[((size_t)(m * KT + kt) * 64 + lane) * 8];
        acc[m][0] = __builtin_amdgcn_mfma_f32_16x16x32_bf16(a, b0, acc[m][0], 0, 0, 0);
        acc[m][1] = __builtin_amdgcn_mfma_f32_16x16x32_bf16(a, b1, acc[m][1], 0, 0, 0);
      }
    }
    if constexpr (!LAST) {
#pragma unroll
      for (int m = 0; m < 2; ++m) {
        float4 bv = *(const float4*)&bwl[(2 * c + m) * 16 + 4 * q];
#pragma unroll
        for (int g = 0; g < 2; ++g) {
          float v0 = fmaxf(acc[m][g][0] + bv.x, 0.f);
          float v1 = fmaxf(acc[m][g][1] + bv.y, 0.f);
          float v2 = fmaxf(acc[m][g][2] + bv.z, 0.f);
          float v3 = fmaxf(acc[m][g][3] + bv.w, 0.f);
          hout[c][g][m * 2 + 0] = pack2(v0, v1);
          hout[c][g][m * 2 + 1] = pack2(v2, v3);
        }
      }
    } else {
#pragma unroll
      for (int m = 0; m < 2; ++m) {
        float4 bv  = *(const float4*)&bwl[(2 * c + m) * 16 + 4 * q];
        float4 wv4 = *(const float4*)&w4t[(2 * c + m) * 16 + 4 * q];
        float v;
        v = fmaxf(acc[m][0][0] + bv.x, 0.f); partial0 += v * wv4.x;
        v = fmaxf(acc[m][0][1] + bv.y, 0.f); partial0 += v * wv4.y;
        v = fmaxf(acc[m][0][2] + bv.z, 0.f); partial0 += v * wv4.z;
        v = fmaxf(acc[m][0][3] + bv.w, 0.f); partial0 += v * wv4.w;
        v = fmaxf(acc[m][1][0] + bv.x, 0.f); partial1 += v * wv4.x;
        v = fmaxf(acc[m][1][1] + bv.y, 0.f); partial1 += v * wv4.y;
        v = fmaxf(acc[m][1][2] + bv.z, 0.f); partial1 += v * wv4.z;
        v = fmaxf(acc[m][1][3] + bv.w, 0.f); partial1 += v * wv4.w;
      }
    }
    __syncthreads();
    (void)NB;
  }
}

// ---------------------------------------------------------------------------
// Fused kernel. 256 threads = 4 waves; wave owns 32 points (2 groups of 16).
// Activations in registers (huA/huB alternate); weights stream through two
// 16KB LDS chunk buffers via async global_load_lds, one chunk ahead.
// ---------------------------------------------------------------------------
template <typename TI>
__global__ __launch_bounds__(256, 3) void lisa_fused_t(
    const TI* __restrict__ coord, const TI* __restrict__ latent,
    const TI* __restrict__ bias0, const TI* __restrict__ bias1,
    const TI* __restrict__ bias2, const TI* __restrict__ bias3,
    const TI* __restrict__ W4,    const TI* __restrict__ b4,
    const ushort_t* __restrict__ pw, TI* __restrict__ out,
    const int* __restrict__ flag, int want)
{
  if (*flag != want) return;
  __shared__ __align__(16) ushort_t wbuf[2][8192];       // 2 x 16 KB chunks
  __shared__ __align__(16) float bw[4 * 256 + 256 + 1];  // biases | w4 | b4

  const int tid  = threadIdx.x;
  const int lane = tid & 63, q = lane >> 4, m15 = lane & 15;
  const int wv   = tid >> 6;
  const long pbase = (long)blockIdx.x * 128 + wv * 32 + m15;  // group g adds 16

  // ---- stage chunk 0 (async) + bias/w4 table ----
  stage_idx(0, wbuf[0], pw, tid);
  for (int i = tid; i < 1281; i += 256) {
    float v;
    if (i < 256)       v = ldv(bias0, i);
    else if (i < 512)  v = ldv(bias1, i - 256);
    else if (i < 768)  v = ldv(bias2, i - 512);
    else if (i < 1024) v = ldv(bias3, i - 768);
    else if (i < 1280) v = ldv(W4, i - 1024);
    else               v = ldv(b4, 0);
    bw[i] = v;
  }

  // ---- feature build directly into sigma-ordered B-frags (registers) ----
  uint4v huA[8][2], huB[8][2];
#pragma unroll
  for (int g = 0; g < 2; ++g) {
    long p = pbase + g * 16;
    float c   = ldv(coord, p);
    float ixv = c * 2048.0f - 0.5f;
    float x0f = floorf(ixv);
    float t   = ixv - x0f;
    int   x0  = (int)x0f;
    int   i0  = imin(imax(x0, 0), NLAT - 1);
    int   i1  = imin(imax(x0 + 1, 0), NLAT - 1);
    float w0 = 1.0f - t, w1 = t;
    int rows0[3] = { imax(i0 - 1, 0), i0, imin(i0 + 1, NLAT - 1) };
    int rows1[3] = { imax(i1 - 1, 0), i1, imin(i1 + 1, NLAT - 1) };
    const TI* lat = latent + (size_t)(p >> 15) * (NLAT * DLAT);
#pragma unroll
    for (int tb = 0; tb < 12; ++tb) {
      int region = tb >> 2;
      int d0 = 16 * (tb & 3) + 4 * q;
      float4 a = load4f(lat + (long)rows0[region] * DLAT + d0);
      float4 b = load4f(lat + (long)rows1[region] * DLAT + d0);
      huA[tb >> 1][g][(tb & 1) * 2 + 0] = pack2(w0 * a.x + w1 * b.x, w0 * a.y + w1 * b.y);
      huA[tb >> 1][g][(tb & 1) * 2 + 1] = pack2(w0 * a.z + w1 * b.z, w0 * a.w + w1 * b.w);
    }
    float pv[4];
#pragma unroll
    for (int s = 0; s < 4; ++s) {
      int f = 192 + 4 * q + s;
      float v = 0.0f;
      if (f == 192) v = c;
      else if (f <= 204) {
        int i = f - 193;
        float fr = (float)(1 << (i >> 1));
        float ang = c * fr;
        v = (i & 1) ? __cosf(ang) : __sinf(ang);
      }
      pv[s] = v;
    }
    huA[6][g][0] = pack2(pv[0], pv[1]);
    huA[6][g][1] = pack2(pv[2], pv[3]);
    huA[6][g][2] = 0; huA[6][g][3] = 0;
  }
  __syncthreads();   // chunk 0 ready (vmcnt drained at barrier), table ready

  float partial0 = 0.f, partial1 = 0.f;
  layer_run<7,  0, false>(huA, huB, bw + 0 * 256, bw + 1024, wbuf, pw, tid, lane, q, partial0, partial1);
  layer_run<8,  8, false>(huB, huA, bw + 1 * 256, bw + 1024, wbuf, pw, tid, lane, q, partial0, partial1);
  layer_run<8, 16, false>(huA, huB, bw + 2 * 256, bw + 1024, wbuf, pw, tid, lane, q, partial0, partial1);
  layer_run<8, 24, true >(huB, huA, bw + 3 * 256, bw + 1024, wbuf, pw, tid, lane, q, partial0, partial1);

  // ---- reduce the 4 channel-quads of each point, store ----
  partial0 += __shfl_xor(partial0, 16, 64);
  partial0 += __shfl_xor(partial0, 32, 64);
  partial1 += __shfl_xor(partial1, 16, 64);
  partial1 += __shfl_xor(partial1, 32, 64);
  if (lane < 16) {
    float bb = bw[1280];
    stv(out, pbase,      partial0 + bb);
    stv(out, pbase + 16, partial1 + bb);
  }
}

extern "C" void kernel_launch(void* const* d_in, const int* in_sizes, int n_in,
                              void* d_out, int out_size, void* d_ws, size_t ws_size,
                              hipStream_t stream) {
  int* flag = (int*)d_ws;
  ushort_t* pw = (ushort_t*)d_ws + PW_BASE;

  detect_mode<<<1, 64, 0, stream>>>((const ushort_t*)d_in[1], flag);

  // fp32-input variant (flag==1)
  pack_w_t<float><<<62, 512, 0, stream>>>(
      (const float*)d_in[2], (const float*)d_in[4], (const float*)d_in[6],
      (const float*)d_in[8], pw, flag, 1);
  lisa_fused_t<float><<<2048, 256, 0, stream>>>(
      (const float*)d_in[0], (const float*)d_in[1],
      (const float*)d_in[3], (const float*)d_in[5], (const float*)d_in[7],
      (const float*)d_in[9], (const float*)d_in[10], (const float*)d_in[11],
      pw, (float*)d_out, flag, 1);

  // bf16-input variant (flag==0)
  pack_w_t<ushort_t><<<62, 512, 0, stream>>>(
      (const ushort_t*)d_in[2], (const ushort_t*)d_in[4], (const ushort_t*)d_in[6],
      (const ushort_t*)d_in[8], pw, flag, 0);
  lisa_fused_t<ushort_t><<<2048, 256, 0, stream>>>(
      (const ushort_t*)d_in[0], (const ushort_t*)d_in[1],
      (const ushort_t*)d_in[3], (const ushort_t*)d_in[5], (const ushort_t*)d_in[7],
      (const ushort_t*)d_in[9], (const ushort_t*)d_in[10], (const ushort_t*)d_in[11],
      pw, (ushort_t*)d_out, flag, 0);
}

// Round 9
// 245.739 us; speedup vs baseline: 1.8261x; 1.8261x over previous
//
#include <hip/hip_runtime.h>

typedef unsigned short ushort_t;
typedef unsigned int uint_t;
typedef __attribute__((ext_vector_type(8))) short short8;
typedef __attribute__((ext_vector_type(4))) float float4v;
typedef __attribute__((ext_vector_type(4))) uint_t uint4v;

#define NLAT 2048
#define DLAT 64

// d_ws layout (ushort units): [0..127] flag area (int at byte 0), then packed weights
#define PW_BASE 128
#define PW0_OFF 0        // layer0: KT=7 -> 7*16*64*8 = 57344 ushorts
#define PW1_OFF 57344    // KT=8 -> 65536 each
#define PW2_OFF 122880
#define PW3_OFF 188416
// half sizes (ushorts): mt 0-7 frags occupy KT*8*64*8 = KT*4096
#define H7 28672
#define H8 32768

__device__ __forceinline__ float b2f(ushort_t u) {
  union { uint_t i; float f; } v; v.i = ((uint_t)u) << 16; return v.f;
}
__device__ __forceinline__ ushort_t f2b(float f) {
  uint_t x = __float_as_uint(f);
  uint_t r = (x + 0x7fffu + ((x >> 16) & 1u)) >> 16;   // RNE
  return (ushort_t)r;
}
__device__ __forceinline__ uint_t pack2(float lo, float hi) {
  return (uint_t)f2b(lo) | ((uint_t)f2b(hi) << 16);
}
__device__ __forceinline__ int imin(int a, int b) { return a < b ? a : b; }
__device__ __forceinline__ int imax(int a, int b) { return a > b ? a : b; }

__device__ __forceinline__ float ldv(const float* p, long i)    { return p[i]; }
__device__ __forceinline__ float ldv(const ushort_t* p, long i) { return b2f(p[i]); }
__device__ __forceinline__ void stv(float* p, long i, float v)    { p[i] = v; }
__device__ __forceinline__ void stv(ushort_t* p, long i, float v) { p[i] = f2b(v); }

__device__ __forceinline__ float4 load4f(const float* p) { return *(const float4*)p; }
__device__ __forceinline__ float4 load4f(const ushort_t* p) {
  uint2 u = *(const uint2*)p;
  float4 r;
  r.x = b2f((ushort_t)(u.x & 0xffffu)); r.y = b2f((ushort_t)(u.x >> 16));
  r.z = b2f((ushort_t)(u.y & 0xffffu)); r.w = b2f((ushort_t)(u.y >> 16));
  return r;
}

// async 16B/lane global->LDS copy (gfx950 global_load_lds_dwordx4)
__device__ __forceinline__ void async_copy16(const ushort_t* g, ushort_t* l) {
  __builtin_amdgcn_global_load_lds(
      (const __attribute__((address_space(1))) void*)g,
      (__attribute__((address_space(3))) void*)l, 16, 0, 0);
}
// stage the LDS-fed 5-mt slice of a half (first 5*KT frags, contiguous):
// 5*KT*64 16B units, 512 threads
__device__ __forceinline__ void stage_half(ushort_t* dst, const ushort_t* src,
                                           int KT, int tid) {
  int n = KT * 320;
  for (int i = tid; i < n; i += 512)
    async_copy16(src + (size_t)i * 8, dst + (size_t)i * 8);
}

// ---------------------------------------------------------------------------
// Runtime dtype probe: flag=1 -> fp32 inputs, flag=0 -> bf16
// ---------------------------------------------------------------------------
__global__ void detect_mode(const ushort_t* __restrict__ lat, int* __restrict__ flag) {
  if (threadIdx.x == 0) *flag = 0;
  __syncthreads();
  int big = 0;
  for (int i = threadIdx.x; i < 1024; i += 64) {
    float v = b2f(lat[i]);
    if (!(fabsf(v) < 1e5f)) big = 1;
  }
  if (__any(big) && threadIdx.x == 0) *flag = 1;
}

// ---------------------------------------------------------------------------
// Pack weights as MFMA A-fragments (A = W^T, m = chan_out), sigma k-permuted
// to match the C-register order of the previous layer:
//   element j of frag(mt,kt,lane) = W[sigma][mt*16 + (lane&15)]
//   sigma = 32*kt + 16*(j>>2) + 4*(lane>>4) + (j&3)
// Layer 0: sigma indexes [sampled(192) | coord | pe(12) | pad->224].
// ---------------------------------------------------------------------------
template <typename TI>
__global__ void pack_w_t(const TI* __restrict__ W0, const TI* __restrict__ W1,
                         const TI* __restrict__ W2, const TI* __restrict__ W3,
                         ushort_t* __restrict__ pw, const int* __restrict__ flag, int want)
{
  if (*flag != want) return;
  int g = blockIdx.x * blockDim.x + threadIdx.x;
  if (g >= 31 * 1024) return;
  int lane = g & 63, q = lane >> 4;
  int mt   = (g >> 6) & 15;
  int ktg  = g >> 10;                       // 0..30
  const TI* W; ushort_t* dst; int kt, KT; bool isw0 = false;
  if (ktg < 7)       { W = W0; dst = pw + PW0_OFF; kt = ktg;      KT = 7; isw0 = true; }
  else if (ktg < 15) { W = W1; dst = pw + PW1_OFF; kt = ktg - 7;  KT = 8; }
  else if (ktg < 23) { W = W2; dst = pw + PW2_OFF; kt = ktg - 15; KT = 8; }
  else               { W = W3; dst = pw + PW3_OFF; kt = ktg - 23; KT = 8; }
  int col = mt * 16 + (lane & 15);
  uint_t words[4];
#pragma unroll
  for (int h = 0; h < 4; ++h) {
    ushort_t vv[2];
#pragma unroll
    for (int e = 0; e < 2; ++e) {
      int j = 2 * h + e;
      int f = 32 * kt + 16 * (j >> 2) + 4 * q + (j & 3);
      int row = f;
      if (isw0) row = (f < 192) ? (13 + f) : (f == 192 ? 0 : (f <= 204 ? f - 192 : -1));
      vv[e] = (row >= 0) ? f2b(ldv(W, (long)row * 256 + col)) : (ushort_t)0;
    }
    words[h] = (uint_t)vv[0] | ((uint_t)vv[1] << 16);
  }
  uint4 o; o.x = words[0]; o.y = words[1]; o.z = words[2]; o.w = words[3];
  *(uint4*)(dst + ((size_t)(mt * KT + kt) * 64 + lane) * 8) = o;
}

// ---------------------------------------------------------------------------
// Compute one half-layer (8 mt tiles): mt 0-4 A-frags from LDS (staged),
// mt 5-7 straight from global (L1/L2-hot, all waves read identical lines).
// Global loads issued FIRST each kt for max latency distance; no branches.
// ---------------------------------------------------------------------------
template <int KT, int MTBASE>
__device__ __forceinline__ void compute_half(float4v (&acc)[16][2],
                                             const uint4v (&hu)[8][2],
                                             const ushort_t* buf,
                                             const ushort_t* __restrict__ gsrc,
                                             int lane)
{
#pragma unroll
  for (int m = 0; m < 8; ++m) {
    acc[MTBASE + m][0] = (float4v){0.f, 0.f, 0.f, 0.f};
    acc[MTBASE + m][1] = (float4v){0.f, 0.f, 0.f, 0.f};
  }
#pragma unroll
  for (int kt = 0; kt < KT; ++kt) {
    short8 a[8];
#pragma unroll
    for (int m = 5; m < 8; ++m)   // global first: max distance to use
      a[m] = *(const short8*)&gsrc[((size_t)(m * KT + kt) * 64 + lane) * 8];
#pragma unroll
    for (int m = 0; m < 5; ++m)
      a[m] = *(const short8*)&buf[((size_t)(m * KT + kt) * 64 + lane) * 8];
    short8 b0 = __builtin_bit_cast(short8, hu[kt][0]);
    short8 b1 = __builtin_bit_cast(short8, hu[kt][1]);
#pragma unroll
    for (int m = 0; m < 8; ++m) {
      acc[MTBASE + m][0] = __builtin_amdgcn_mfma_f32_16x16x32_bf16(a[m], b0, acc[MTBASE + m][0], 0, 0, 0);
      acc[MTBASE + m][1] = __builtin_amdgcn_mfma_f32_16x16x32_bf16(a[m], b1, acc[MTBASE + m][1], 0, 0, 0);
    }
  }
}

// acc -> bias+relu+bf16 pack -> hu (B operand of next layer, sigma order)
__device__ __forceinline__ void convert_layer(float4v (&acc)[16][2], uint4v (&hu)[8][2],
                                              const float* bwl, int q)
{
#pragma unroll
  for (int mt = 0; mt < 16; ++mt) {
    float4 b4 = *(const float4*)&bwl[mt * 16 + 4 * q];
#pragma unroll
    for (int g = 0; g < 2; ++g) {
      float v0 = fmaxf(acc[mt][g][0] + b4.x, 0.f);
      float v1 = fmaxf(acc[mt][g][1] + b4.y, 0.f);
      float v2 = fmaxf(acc[mt][g][2] + b4.z, 0.f);
      float v3 = fmaxf(acc[mt][g][3] + b4.w, 0.f);
      hu[mt >> 1][g][(mt & 1) * 2 + 0] = pack2(v0, v1);
      hu[mt >> 1][g][(mt & 1) * 2 + 1] = pack2(v2, v3);
    }
  }
}

// ---------------------------------------------------------------------------
// Fused kernel. 512 threads = 8 waves; wave owns 32 points (2 groups of 16).
// Activations in registers; weight feed split: 5/8 via LDS ping-pong staging
// (global_load_lds), 3/8 direct from L1/L2-hot global — parallel pipes.
// ---------------------------------------------------------------------------
template <typename TI>
__global__ __launch_bounds__(512, 2) void lisa_fused_t(
    const TI* __restrict__ coord, const TI* __restrict__ latent,
    const TI* __restrict__ bias0, const TI* __restrict__ bias1,
    const TI* __restrict__ bias2, const TI* __restrict__ bias3,
    const TI* __restrict__ W4,    const TI* __restrict__ b4,
    const ushort_t* __restrict__ pw, TI* __restrict__ out,
    const int* __restrict__ flag, int want)
{
  if (*flag != want) return;
  __shared__ __align__(16) ushort_t wbuf[2][20480];      // 2 x 40 KB (5-mt slices)
  __shared__ __align__(16) float bw[4 * 256 + 256 + 1];  // biases | w4 | b4

  const int tid  = threadIdx.x;
  const int lane = tid & 63, q = lane >> 4, m15 = lane & 15;
  const int wv   = tid >> 6;
  const long pbase = (long)blockIdx.x * 256 + wv * 32 + m15;  // group g adds 16

  // ---- stage L0 half0 LDS-slice (async) + bias/w4 table ----
  stage_half(wbuf[0], pw + PW0_OFF, 7, tid);
  for (int i = tid; i < 1281; i += 512) {
    float v;
    if (i < 256)       v = ldv(bias0, i);
    else if (i < 512)  v = ldv(bias1, i - 256);
    else if (i < 768)  v = ldv(bias2, i - 512);
    else if (i < 1024) v = ldv(bias3, i - 768);
    else if (i < 1280) v = ldv(W4, i - 1024);
    else               v = ldv(b4, 0);
    bw[i] = v;
  }

  // ---- feature build directly into sigma-ordered B-frags (registers) ----
  uint4v hu[8][2];
#pragma unroll
  for (int g = 0; g < 2; ++g) {
    long p = pbase + g * 16;
    float c   = ldv(coord, p);
    float ixv = c * 2048.0f - 0.5f;
    float x0f = floorf(ixv);
    float t   = ixv - x0f;
    int   x0  = (int)x0f;
    int   i0  = imin(imax(x0, 0), NLAT - 1);
    int   i1  = imin(imax(x0 + 1, 0), NLAT - 1);
    float w0 = 1.0f - t, w1 = t;
    int rows0[3] = { imax(i0 - 1, 0), i0, imin(i0 + 1, NLAT - 1) };
    int rows1[3] = { imax(i1 - 1, 0), i1, imin(i1 + 1, NLAT - 1) };
    const TI* lat = latent + (size_t)(p >> 15) * (NLAT * DLAT);
#pragma unroll
    for (int tb = 0; tb < 12; ++tb) {
      int region = tb >> 2;
      int d0 = 16 * (tb & 3) + 4 * q;
      float4 a = load4f(lat + (long)rows0[region] * DLAT + d0);
      float4 b = load4f(lat + (long)rows1[region] * DLAT + d0);
      hu[tb >> 1][g][(tb & 1) * 2 + 0] = pack2(w0 * a.x + w1 * b.x, w0 * a.y + w1 * b.y);
      hu[tb >> 1][g][(tb & 1) * 2 + 1] = pack2(w0 * a.z + w1 * b.z, w0 * a.w + w1 * b.w);
    }
    float pv[4];
#pragma unroll
    for (int s = 0; s < 4; ++s) {
      int f = 192 + 4 * q + s;
      float v = 0.0f;
      if (f == 192) v = c;
      else if (f <= 204) {
        int i = f - 193;
        float fr = (float)(1 << (i >> 1));
        float ang = c * fr;
        v = (i & 1) ? __cosf(ang) : __sinf(ang);
      }
      pv[s] = v;
    }
    hu[6][g][0] = pack2(pv[0], pv[1]);
    hu[6][g][1] = pack2(pv[2], pv[3]);
    hu[6][g][2] = 0; hu[6][g][3] = 0;
  }
  __syncthreads();   // wbuf[0] ready (vmcnt drained), table ready

  float4v acc[16][2];

  // ---- layer 0 (KT=7) ----
  stage_half(wbuf[1], pw + PW0_OFF + H7, 7, tid);
  compute_half<7, 0>(acc, hu, wbuf[0], pw + PW0_OFF, lane);
  __syncthreads();
  stage_half(wbuf[0], pw + PW1_OFF, 8, tid);
  compute_half<7, 8>(acc, hu, wbuf[1], pw + PW0_OFF + H7, lane);
  convert_layer(acc, hu, bw + 0 * 256, q);
  __syncthreads();

  // ---- layer 1 ----
  stage_half(wbuf[1], pw + PW1_OFF + H8, 8, tid);
  compute_half<8, 0>(acc, hu, wbuf[0], pw + PW1_OFF, lane);
  __syncthreads();
  stage_half(wbuf[0], pw + PW2_OFF, 8, tid);
  compute_half<8, 8>(acc, hu, wbuf[1], pw + PW1_OFF + H8, lane);
  convert_layer(acc, hu, bw + 1 * 256, q);
  __syncthreads();

  // ---- layer 2 ----
  stage_half(wbuf[1], pw + PW2_OFF + H8, 8, tid);
  compute_half<8, 0>(acc, hu, wbuf[0], pw + PW2_OFF, lane);
  __syncthreads();
  stage_half(wbuf[0], pw + PW3_OFF, 8, tid);
  compute_half<8, 8>(acc, hu, wbuf[1], pw + PW2_OFF + H8, lane);
  convert_layer(acc, hu, bw + 2 * 256, q);
  __syncthreads();

  // ---- layer 3 ----
  stage_half(wbuf[1], pw + PW3_OFF + H8, 8, tid);
  compute_half<8, 0>(acc, hu, wbuf[0], pw + PW3_OFF, lane);
  __syncthreads();
  compute_half<8, 8>(acc, hu, wbuf[1], pw + PW3_OFF + H8, lane);

  // ---- final: bias3+relu fused with 256->1 dot against w4 ----
  float partial0 = 0.f, partial1 = 0.f;
#pragma unroll
  for (int mt = 0; mt < 16; ++mt) {
    float4 b3v = *(const float4*)&bw[3 * 256 + mt * 16 + 4 * q];
    float4 w4v = *(const float4*)&bw[1024 + mt * 16 + 4 * q];
    float v;
    v = fmaxf(acc[mt][0][0] + b3v.x, 0.f); partial0 += v * w4v.x;
    v = fmaxf(acc[mt][0][1] + b3v.y, 0.f); partial0 += v * w4v.y;
    v = fmaxf(acc[mt][0][2] + b3v.z, 0.f); partial0 += v * w4v.z;
    v = fmaxf(acc[mt][0][3] + b3v.w, 0.f); partial0 += v * w4v.w;
    v = fmaxf(acc[mt][1][0] + b3v.x, 0.f); partial1 += v * w4v.x;
    v = fmaxf(acc[mt][1][1] + b3v.y, 0.f); partial1 += v * w4v.y;
    v = fmaxf(acc[mt][1][2] + b3v.z, 0.f); partial1 += v * w4v.z;
    v = fmaxf(acc[mt][1][3] + b3v.w, 0.f); partial1 += v * w4v.w;
  }
  partial0 += __shfl_xor(partial0, 16, 64);
  partial0 += __shfl_xor(partial0, 32, 64);
  partial1 += __shfl_xor(partial1, 16, 64);
  partial1 += __shfl_xor(partial1, 32, 64);
  if (lane < 16) {
    float bb = bw[1280];
    stv(out, pbase,      partial0 + bb);
    stv(out, pbase + 16, partial1 + bb);
  }
}

extern "C" void kernel_launch(void* const* d_in, const int* in_sizes, int n_in,
                              void* d_out, int out_size, void* d_ws, size_t ws_size,
                              hipStream_t stream) {
  int* flag = (int*)d_ws;
  ushort_t* pw = (ushort_t*)d_ws + PW_BASE;

  detect_mode<<<1, 64, 0, stream>>>((const ushort_t*)d_in[1], flag);

  // fp32-input variant (flag==1)
  pack_w_t<float><<<62, 512, 0, stream>>>(
      (const float*)d_in[2], (const float*)d_in[4], (const float*)d_in[6],
      (const float*)d_in[8], pw, flag, 1);
  lisa_fused_t<float><<<1024, 512, 0, stream>>>(
      (const float*)d_in[0], (const float*)d_in[1],
      (const float*)d_in[3], (const float*)d_in[5], (const float*)d_in[7],
      (const float*)d_in[9], (const float*)d_in[10], (const float*)d_in[11],
      pw, (float*)d_out, flag, 1);

  // bf16-input variant (flag==0)
  pack_w_t<ushort_t><<<62, 512, 0, stream>>>(
      (const ushort_t*)d_in[2], (const ushort_t*)d_in[4], (const ushort_t*)d_in[6],
      (const ushort_t*)d_in[8], pw, flag, 0);
  lisa_fused_t<ushort_t><<<1024, 512, 0, stream>>>(
      (const ushort_t*)d_in[0], (const ushort_t*)d_in[1],
      (const ushort_t*)d_in[3], (const ushort_t*)d_in[5], (const ushort_t*)d_in[7],
      (const ushort_t*)d_in[9], (const ushort_t*)d_in[10], (const ushort_t*)d_in[11],
      pw, (ushort_t*)d_out, flag, 0);
}

// Round 10
// 236.730 us; speedup vs baseline: 1.8956x; 1.0381x over previous
//
#include <hip/hip_runtime.h>
#include <hip/hip_bf16.h>

typedef unsigned short ushort_t;
typedef unsigned int uint_t;
typedef __attribute__((ext_vector_type(8))) short short8;
typedef __attribute__((ext_vector_type(4))) float float4v;
typedef __attribute__((ext_vector_type(4))) uint_t uint4v;

#define NLAT 2048
#define DLAT 64

// d_ws layout (ushort units): [0..127] flag area (int at byte 0), then packed weights
#define PW_BASE 128
#define PW0_OFF 0        // layer0: KT=7 -> 7*16*64*8 = 57344 ushorts
#define PW1_OFF 57344    // KT=8 -> 65536 each
#define PW2_OFF 122880
#define PW3_OFF 188416

__device__ __forceinline__ float b2f(ushort_t u) {
  union { uint_t i; float f; } v; v.i = ((uint_t)u) << 16; return v.f;
}
__device__ __forceinline__ ushort_t f2b(float f) {
  uint_t x = __float_as_uint(f);
  uint_t r = (x + 0x7fffu + ((x >> 16) & 1u)) >> 16;   // RNE
  return (ushort_t)r;
}
// HW packed f32x2 -> bf16x2 (v_cvt_pk_bf16_f32), replaces ~8-op manual RNE
__device__ __forceinline__ uint_t pack2(float lo, float hi) {
  float2 t; t.x = lo; t.y = hi;
  union { __hip_bfloat162 h; uint_t u; } cv;
  cv.h = __float22bfloat162_rn(t);
  return cv.u;
}
__device__ __forceinline__ int imin(int a, int b) { return a < b ? a : b; }
__device__ __forceinline__ int imax(int a, int b) { return a > b ? a : b; }

__device__ __forceinline__ float ldv(const float* p, long i)    { return p[i]; }
__device__ __forceinline__ float ldv(const ushort_t* p, long i) { return b2f(p[i]); }
__device__ __forceinline__ void stv(float* p, long i, float v)    { p[i] = v; }
__device__ __forceinline__ void stv(ushort_t* p, long i, float v) { p[i] = f2b(v); }

__device__ __forceinline__ float4 load4f(const float* p) { return *(const float4*)p; }
__device__ __forceinline__ float4 load4f(const ushort_t* p) {
  uint2 u = *(const uint2*)p;
  float4 r;
  r.x = b2f((ushort_t)(u.x & 0xffffu)); r.y = b2f((ushort_t)(u.x >> 16));
  r.z = b2f((ushort_t)(u.y & 0xffffu)); r.w = b2f((ushort_t)(u.y >> 16));
  return r;
}

// async 16B/lane global->LDS copy (gfx950 global_load_lds_dwordx4)
__device__ __forceinline__ void async_copy16(const ushort_t* g, ushort_t* l) {
  __builtin_amdgcn_global_load_lds(
      (const __attribute__((address_space(1))) void*)g,
      (__attribute__((address_space(3))) void*)l, 16, 0, 0);
}

// ---------------------------------------------------------------------------
// Stage weight quarter gi (0..15): layer gi>>2, quarter q=gi&3 (4 mt-tiles,
// KT*2048 ushorts, contiguous). 256 threads.
// ---------------------------------------------------------------------------
__device__ __forceinline__ void stage_q(int gi, ushort_t* dst,
                                        const ushort_t* __restrict__ pw, int tid) {
  int layer = gi >> 2, q = gi & 3;
  int KT = (layer == 0) ? 7 : 8;
  int loff = (layer == 0) ? PW0_OFF : (layer == 1) ? PW1_OFF
           : (layer == 2) ? PW2_OFF : PW3_OFF;
  const ushort_t* src = pw + loff + q * KT * 2048;
  int n = KT * 256;                        // 16B issues
  for (int i = tid; i < n; i += 256)
    async_copy16(src + (size_t)i * 8, dst + (size_t)i * 8);
}

// ---------------------------------------------------------------------------
// Runtime dtype probe: flag=1 -> fp32 inputs, flag=0 -> bf16
// ---------------------------------------------------------------------------
__global__ void detect_mode(const ushort_t* __restrict__ lat, int* __restrict__ flag) {
  if (threadIdx.x == 0) *flag = 0;
  __syncthreads();
  int big = 0;
  for (int i = threadIdx.x; i < 1024; i += 64) {
    float v = b2f(lat[i]);
    if (!(fabsf(v) < 1e5f)) big = 1;
  }
  if (__any(big) && threadIdx.x == 0) *flag = 1;
}

// ---------------------------------------------------------------------------
// Pack weights as MFMA A-fragments (A = W^T, m = chan_out), sigma k-permuted
// to match the C-register order of the previous layer:
//   element j of frag(mt,kt,lane) = W[sigma][mt*16 + (lane&15)]
//   sigma = 32*kt + 16*(j>>2) + 4*(lane>>4) + (j&3)
// Layer 0: sigma indexes [sampled(192) | coord | pe(12) | pad->224].
// ---------------------------------------------------------------------------
template <typename TI>
__global__ void pack_w_t(const TI* __restrict__ W0, const TI* __restrict__ W1,
                         const TI* __restrict__ W2, const TI* __restrict__ W3,
                         ushort_t* __restrict__ pw, const int* __restrict__ flag, int want)
{
  if (*flag != want) return;
  int g = blockIdx.x * blockDim.x + threadIdx.x;
  if (g >= 31 * 1024) return;
  int lane = g & 63, q = lane >> 4;
  int mt   = (g >> 6) & 15;
  int ktg  = g >> 10;                       // 0..30
  const TI* W; ushort_t* dst; int kt, KT; bool isw0 = false;
  if (ktg < 7)       { W = W0; dst = pw + PW0_OFF; kt = ktg;      KT = 7; isw0 = true; }
  else if (ktg < 15) { W = W1; dst = pw + PW1_OFF; kt = ktg - 7;  KT = 8; }
  else if (ktg < 23) { W = W2; dst = pw + PW2_OFF; kt = ktg - 15; KT = 8; }
  else               { W = W3; dst = pw + PW3_OFF; kt = ktg - 23; KT = 8; }
  int col = mt * 16 + (lane & 15);
  uint_t words[4];
#pragma unroll
  for (int h = 0; h < 4; ++h) {
    ushort_t vv[2];
#pragma unroll
    for (int e = 0; e < 2; ++e) {
      int j = 2 * h + e;
      int f = 32 * kt + 16 * (j >> 2) + 4 * q + (j & 3);
      int row = f;
      if (isw0) row = (f < 192) ? (13 + f) : (f == 192 ? 0 : (f <= 204 ? f - 192 : -1));
      vv[e] = (row >= 0) ? f2b(ldv(W, (long)row * 256 + col)) : (ushort_t)0;
    }
    words[h] = (uint_t)vv[0] | ((uint_t)vv[1] << 16);
  }
  uint4 o; o.x = words[0]; o.y = words[1]; o.z = words[2]; o.w = words[3];
  *(uint4*)(dst + ((size_t)(mt * KT + kt) * 64 + lane) * 8) = o;
}

// ---------------------------------------------------------------------------
// One layer = 4 quarter-passes (4 mt-tiles each) from ping-ponged 32KB LDS
// buffers; stage quarter gi+1 while computing gi. Pure ds_read_b128 -> MFMA.
// ---------------------------------------------------------------------------
template <int KT>
__device__ __forceinline__ void run_layer(int base, float4v (&acc)[16][2],
                                          const uint4v (&hu)[8][2],
                                          ushort_t (*wbuf)[16384],
                                          const ushort_t* __restrict__ pw,
                                          int tid, int lane)
{
#pragma unroll
  for (int qq = 0; qq < 4; ++qq) {
    const int gi = base + qq;
    if (gi + 1 < 16) stage_q(gi + 1, wbuf[(gi + 1) & 1], pw, tid);
    const ushort_t* buf = wbuf[gi & 1];
#pragma unroll
    for (int m = 0; m < 4; ++m) {
      acc[qq * 4 + m][0] = (float4v){0.f, 0.f, 0.f, 0.f};
      acc[qq * 4 + m][1] = (float4v){0.f, 0.f, 0.f, 0.f};
    }
#pragma unroll
    for (int kt = 0; kt < KT; ++kt) {
      short8 b0 = __builtin_bit_cast(short8, hu[kt][0]);
      short8 b1 = __builtin_bit_cast(short8, hu[kt][1]);
#pragma unroll
      for (int m = 0; m < 4; ++m) {
        short8 a = *(const short8*)&buf[((size_t)(m * KT + kt) * 64 + lane) * 8];
        acc[qq * 4 + m][0] = __builtin_amdgcn_mfma_f32_16x16x32_bf16(a, b0, acc[qq * 4 + m][0], 0, 0, 0);
        acc[qq * 4 + m][1] = __builtin_amdgcn_mfma_f32_16x16x32_bf16(a, b1, acc[qq * 4 + m][1], 0, 0, 0);
      }
    }
    __syncthreads();
  }
}

// acc -> bias+relu+bf16 pack -> hu (B operand of next layer, sigma order)
__device__ __forceinline__ void convert_layer(float4v (&acc)[16][2], uint4v (&hu)[8][2],
                                              const float* bwl, int q)
{
#pragma unroll
  for (int mt = 0; mt < 16; ++mt) {
    float4 b4 = *(const float4*)&bwl[mt * 16 + 4 * q];
#pragma unroll
    for (int g = 0; g < 2; ++g) {
      float v0 = fmaxf(acc[mt][g][0] + b4.x, 0.f);
      float v1 = fmaxf(acc[mt][g][1] + b4.y, 0.f);
      float v2 = fmaxf(acc[mt][g][2] + b4.z, 0.f);
      float v3 = fmaxf(acc[mt][g][3] + b4.w, 0.f);
      hu[mt >> 1][g][(mt & 1) * 2 + 0] = pack2(v0, v1);
      hu[mt >> 1][g][(mt & 1) * 2 + 1] = pack2(v2, v3);
    }
  }
}

// ---------------------------------------------------------------------------
// Fused kernel. 256 threads = 4 waves (wave owns 32 points); TWO independent
// blocks per CU so barriers/convert of one block overlap compute of the other.
// Activations in registers; weights stream through 2x32KB LDS quarter buffers.
// ---------------------------------------------------------------------------
template <typename TI>
__global__ __launch_bounds__(256, 2) void lisa_fused_t(
    const TI* __restrict__ coord, const TI* __restrict__ latent,
    const TI* __restrict__ bias0, const TI* __restrict__ bias1,
    const TI* __restrict__ bias2, const TI* __restrict__ bias3,
    const TI* __restrict__ W4,    const TI* __restrict__ b4,
    const ushort_t* __restrict__ pw, TI* __restrict__ out,
    const int* __restrict__ flag, int want)
{
  if (*flag != want) return;
  __shared__ __align__(16) ushort_t wbuf[2][16384];      // 2 x 32 KB quarters
  __shared__ __align__(16) float bw[4 * 256 + 256 + 1];  // biases | w4 | b4

  const int tid  = threadIdx.x;
  const int lane = tid & 63, q = lane >> 4, m15 = lane & 15;
  const int wv   = tid >> 6;                              // 0..3
  const long pbase = (long)blockIdx.x * 128 + wv * 32 + m15;  // group g adds 16

  // ---- stage L0 quarter 0 (async) + bias/w4 table ----
  stage_q(0, wbuf[0], pw, tid);
  for (int i = tid; i < 1281; i += 256) {
    float v;
    if (i < 256)       v = ldv(bias0, i);
    else if (i < 512)  v = ldv(bias1, i - 256);
    else if (i < 768)  v = ldv(bias2, i - 512);
    else if (i < 1024) v = ldv(bias3, i - 768);
    else if (i < 1280) v = ldv(W4, i - 1024);
    else               v = ldv(b4, 0);
    bw[i] = v;
  }

  // ---- feature build directly into sigma-ordered B-frags (registers) ----
  uint4v hu[8][2];
#pragma unroll
  for (int g = 0; g < 2; ++g) {
    long p = pbase + g * 16;
    float c   = ldv(coord, p);
    float ixv = c * 2048.0f - 0.5f;
    float x0f = floorf(ixv);
    float t   = ixv - x0f;
    int   x0  = (int)x0f;
    int   i0  = imin(imax(x0, 0), NLAT - 1);
    int   i1  = imin(imax(x0 + 1, 0), NLAT - 1);
    float w0 = 1.0f - t, w1 = t;
    int rows0[3] = { imax(i0 - 1, 0), i0, imin(i0 + 1, NLAT - 1) };
    int rows1[3] = { imax(i1 - 1, 0), i1, imin(i1 + 1, NLAT - 1) };
    const TI* lat = latent + (size_t)(p >> 15) * (NLAT * DLAT);
#pragma unroll
    for (int tb = 0; tb < 12; ++tb) {
      int region = tb >> 2;
      int d0 = 16 * (tb & 3) + 4 * q;
      float4 a = load4f(lat + (long)rows0[region] * DLAT + d0);
      float4 b = load4f(lat + (long)rows1[region] * DLAT + d0);
      hu[tb >> 1][g][(tb & 1) * 2 + 0] = pack2(w0 * a.x + w1 * b.x, w0 * a.y + w1 * b.y);
      hu[tb >> 1][g][(tb & 1) * 2 + 1] = pack2(w0 * a.z + w1 * b.z, w0 * a.w + w1 * b.w);
    }
    float pv[4];
#pragma unroll
    for (int s = 0; s < 4; ++s) {
      int f = 192 + 4 * q + s;
      float v = 0.0f;
      if (f == 192) v = c;
      else if (f <= 204) {
        int i = f - 193;
        float fr = (float)(1 << (i >> 1));
        float ang = c * fr;
        v = (i & 1) ? __cosf(ang) : __sinf(ang);
      }
      pv[s] = v;
    }
    hu[6][g][0] = pack2(pv[0], pv[1]);
    hu[6][g][1] = pack2(pv[2], pv[3]);
    hu[6][g][2] = 0; hu[6][g][3] = 0;
  }
  __syncthreads();   // quarter 0 ready (vmcnt drained at barrier), table ready

  float4v acc[16][2];

  run_layer<7>( 0, acc, hu, wbuf, pw, tid, lane);
  convert_layer(acc, hu, bw + 0 * 256, q);
  run_layer<8>( 4, acc, hu, wbuf, pw, tid, lane);
  convert_layer(acc, hu, bw + 1 * 256, q);
  run_layer<8>( 8, acc, hu, wbuf, pw, tid, lane);
  convert_layer(acc, hu, bw + 2 * 256, q);
  run_layer<8>(12, acc, hu, wbuf, pw, tid, lane);

  // ---- final: bias3+relu fused with 256->1 dot against w4 ----
  float partial0 = 0.f, partial1 = 0.f;
#pragma unroll
  for (int mt = 0; mt < 16; ++mt) {
    float4 b3v = *(const float4*)&bw[3 * 256 + mt * 16 + 4 * q];
    float4 w4v = *(const float4*)&bw[1024 + mt * 16 + 4 * q];
    float v;
    v = fmaxf(acc[mt][0][0] + b3v.x, 0.f); partial0 += v * w4v.x;
    v = fmaxf(acc[mt][0][1] + b3v.y, 0.f); partial0 += v * w4v.y;
    v = fmaxf(acc[mt][0][2] + b3v.z, 0.f); partial0 += v * w4v.z;
    v = fmaxf(acc[mt][0][3] + b3v.w, 0.f); partial0 += v * w4v.w;
    v = fmaxf(acc[mt][1][0] + b3v.x, 0.f); partial1 += v * w4v.x;
    v = fmaxf(acc[mt][1][1] + b3v.y, 0.f); partial1 += v * w4v.y;
    v = fmaxf(acc[mt][1][2] + b3v.z, 0.f); partial1 += v * w4v.z;
    v = fmaxf(acc[mt][1][3] + b3v.w, 0.f); partial1 += v * w4v.w;
  }
  partial0 += __shfl_xor(partial0, 16, 64);
  partial0 += __shfl_xor(partial0, 32, 64);
  partial1 += __shfl_xor(partial1, 16, 64);
  partial1 += __shfl_xor(partial1, 32, 64);
  if (lane < 16) {
    float bb = bw[1280];
    stv(out, pbase,      partial0 + bb);
    stv(out, pbase + 16, partial1 + bb);
  }
}

extern "C" void kernel_launch(void* const* d_in, const int* in_sizes, int n_in,
                              void* d_out, int out_size, void* d_ws, size_t ws_size,
                              hipStream_t stream) {
  int* flag = (int*)d_ws;
  ushort_t* pw = (ushort_t*)d_ws + PW_BASE;

  detect_mode<<<1, 64, 0, stream>>>((const ushort_t*)d_in[1], flag);

  // fp32-input variant (flag==1)
  pack_w_t<float><<<62, 512, 0, stream>>>(
      (const float*)d_in[2], (const float*)d_in[4], (const float*)d_in[6],
      (const float*)d_in[8], pw, flag, 1);
  lisa_fused_t<float><<<2048, 256, 0, stream>>>(
      (const float*)d_in[0], (const float*)d_in[1],
      (const float*)d_in[3], (const float*)d_in[5], (const float*)d_in[7],
      (const float*)d_in[9], (const float*)d_in[10], (const float*)d_in[11],
      pw, (float*)d_out, flag, 1);

  // bf16-input variant (flag==0)
  pack_w_t<ushort_t><<<62, 512, 0, stream>>>(
      (const ushort_t*)d_in[2], (const ushort_t*)d_in[4], (const ushort_t*)d_in[6],
      (const ushort_t*)d_in[8], pw, flag, 0);
  lisa_fused_t<ushort_t><<<2048, 256, 0, stream>>>(
      (const ushort_t*)d_in[0], (const ushort_t*)d_in[1],
      (const ushort_t*)d_in[3], (const ushort_t*)d_in[5], (const ushort_t*)d_in[7],
      (const ushort_t*)d_in[9], (const ushort_t*)d_in[10], (const ushort_t*)d_in[11],
      pw, (ushort_t*)d_out, flag, 0);
}

// Round 11
// 226.850 us; speedup vs baseline: 1.9781x; 1.0436x over previous
//
#include <hip/hip_runtime.h>
#include <hip/hip_bf16.h>

typedef unsigned short ushort_t;
typedef unsigned int uint_t;
typedef __attribute__((ext_vector_type(8))) short short8;
typedef __attribute__((ext_vector_type(4))) float float4v;
typedef __attribute__((ext_vector_type(4))) uint_t uint4v;

#define NLAT 2048
#define DLAT 64

// d_ws layout (ushort units): [0..127] flag area (int at byte 0), then packed weights
#define PW_BASE 128
#define PW0_OFF 0        // layer0: KT=7 -> 7*16*64*8 = 57344 ushorts
#define PW1_OFF 57344    // KT=8 -> 65536 each
#define PW2_OFF 122880
#define PW3_OFF 188416

__device__ __forceinline__ float b2f(ushort_t u) {
  union { uint_t i; float f; } v; v.i = ((uint_t)u) << 16; return v.f;
}
__device__ __forceinline__ ushort_t f2b(float f) {
  uint_t x = __float_as_uint(f);
  uint_t r = (x + 0x7fffu + ((x >> 16) & 1u)) >> 16;   // RNE
  return (ushort_t)r;
}
// HW packed f32x2 -> bf16x2 (v_cvt_pk_bf16_f32)
__device__ __forceinline__ uint_t pack2(float lo, float hi) {
  float2 t; t.x = lo; t.y = hi;
  union { __hip_bfloat162 h; uint_t u; } cv;
  cv.h = __float22bfloat162_rn(t);
  return cv.u;
}
__device__ __forceinline__ int imin(int a, int b) { return a < b ? a : b; }
__device__ __forceinline__ int imax(int a, int b) { return a > b ? a : b; }

__device__ __forceinline__ float ldv(const float* p, long i)    { return p[i]; }
__device__ __forceinline__ float ldv(const ushort_t* p, long i) { return b2f(p[i]); }
__device__ __forceinline__ void stv(float* p, long i, float v)    { p[i] = v; }
__device__ __forceinline__ void stv(ushort_t* p, long i, float v) { p[i] = f2b(v); }

__device__ __forceinline__ float4 load4f(const float* p) { return *(const float4*)p; }
__device__ __forceinline__ float4 load4f(const ushort_t* p) {
  uint2 u = *(const uint2*)p;
  float4 r;
  r.x = b2f((ushort_t)(u.x & 0xffffu)); r.y = b2f((ushort_t)(u.x >> 16));
  r.z = b2f((ushort_t)(u.y & 0xffffu)); r.w = b2f((ushort_t)(u.y >> 16));
  return r;
}

// async 16B/lane global->LDS copy (gfx950 global_load_lds_dwordx4)
__device__ __forceinline__ void async_copy16(const ushort_t* g, ushort_t* l) {
  __builtin_amdgcn_global_load_lds(
      (const __attribute__((address_space(1))) void*)g,
      (__attribute__((address_space(3))) void*)l, 16, 0, 0);
}

// Stage one weight quarter (KT*2048 ushorts) -> 32KB LDS buffer, 256 threads,
// fully unrolled (KT issues/thread, no cmp/branch).
template <int KT>
__device__ __forceinline__ void stage_q_t(ushort_t* dst, const ushort_t* src, int tid) {
#pragma unroll
  for (int r = 0; r < KT; ++r) {
    int i = tid + (r << 8);
    async_copy16(src + (size_t)i * 8, dst + (size_t)i * 8);
  }
}
// gi is compile-time constant at all call sites (unrolled loops) -> folds.
__device__ __forceinline__ void stage_gi(int gi, ushort_t* dst,
                                         const ushort_t* __restrict__ pw, int tid) {
  int layer = gi >> 2, q = gi & 3;
  if (layer == 0) {
    stage_q_t<7>(dst, pw + PW0_OFF + q * 7 * 2048, tid);
  } else {
    int loff = (layer == 1) ? PW1_OFF : (layer == 2) ? PW2_OFF : PW3_OFF;
    stage_q_t<8>(dst, pw + loff + q * 8 * 2048, tid);
  }
}

// ---------------------------------------------------------------------------
// Runtime dtype probe: flag=1 -> fp32 inputs, flag=0 -> bf16
// ---------------------------------------------------------------------------
__global__ void detect_mode(const ushort_t* __restrict__ lat, int* __restrict__ flag) {
  if (threadIdx.x == 0) *flag = 0;
  __syncthreads();
  int big = 0;
  for (int i = threadIdx.x; i < 1024; i += 64) {
    float v = b2f(lat[i]);
    if (!(fabsf(v) < 1e5f)) big = 1;
  }
  if (__any(big) && threadIdx.x == 0) *flag = 1;
}

// ---------------------------------------------------------------------------
// Pack weights as MFMA A-fragments (A = W^T, m = chan_out), sigma k-permuted
// to match the C-register order of the previous layer:
//   element j of frag(mt,kt,lane) = W[sigma][mt*16 + (lane&15)]
//   sigma = 32*kt + 16*(j>>2) + 4*(lane>>4) + (j&3)
// Layer 0: sigma indexes [sampled(192) | coord | pe(12) | pad->224].
// ---------------------------------------------------------------------------
template <typename TI>
__global__ void pack_w_t(const TI* __restrict__ W0, const TI* __restrict__ W1,
                         const TI* __restrict__ W2, const TI* __restrict__ W3,
                         ushort_t* __restrict__ pw, const int* __restrict__ flag, int want)
{
  if (*flag != want) return;
  int g = blockIdx.x * blockDim.x + threadIdx.x;
  if (g >= 31 * 1024) return;
  int lane = g & 63, q = lane >> 4;
  int mt   = (g >> 6) & 15;
  int ktg  = g >> 10;                       // 0..30
  const TI* W; ushort_t* dst; int kt, KT; bool isw0 = false;
  if (ktg < 7)       { W = W0; dst = pw + PW0_OFF; kt = ktg;      KT = 7; isw0 = true; }
  else if (ktg < 15) { W = W1; dst = pw + PW1_OFF; kt = ktg - 7;  KT = 8; }
  else if (ktg < 23) { W = W2; dst = pw + PW2_OFF; kt = ktg - 15; KT = 8; }
  else               { W = W3; dst = pw + PW3_OFF; kt = ktg - 23; KT = 8; }
  int col = mt * 16 + (lane & 15);
  uint_t words[4];
#pragma unroll
  for (int h = 0; h < 4; ++h) {
    ushort_t vv[2];
#pragma unroll
    for (int e = 0; e < 2; ++e) {
      int j = 2 * h + e;
      int f = 32 * kt + 16 * (j >> 2) + 4 * q + (j & 3);
      int row = f;
      if (isw0) row = (f < 192) ? (13 + f) : (f == 192 ? 0 : (f <= 204 ? f - 192 : -1));
      vv[e] = (row >= 0) ? f2b(ldv(W, (long)row * 256 + col)) : (ushort_t)0;
    }
    words[h] = (uint_t)vv[0] | ((uint_t)vv[1] << 16);
  }
  uint4 o; o.x = words[0]; o.y = words[1]; o.z = words[2]; o.w = words[3];
  *(uint4*)(dst + ((size_t)(mt * KT + kt) * 64 + lane) * 8) = o;
}

// ---------------------------------------------------------------------------
// One layer = 4 quarter-passes (4 mt-tiles each) from ping-ponged 32KB LDS
// buffers; stage quarter gi+1 while computing gi.
// K-loop software-pipelined with two alternating half-buffers (aL: mt 0-1,
// aH: mt 2-3) so ds_reads of one half overlap MFMAs of the other — removes
// the WAR serialization of a single a[4] buffer at zero extra registers.
// ---------------------------------------------------------------------------
template <int KT>
__device__ __forceinline__ void run_layer(int base, float4v (&acc)[16][2],
                                          const uint4v (&hu)[8][2],
                                          ushort_t (*wbuf)[16384],
                                          const ushort_t* __restrict__ pw,
                                          int tid, int lane)
{
#pragma unroll
  for (int qq = 0; qq < 4; ++qq) {
    const int gi = base + qq;
    if (gi + 1 < 16) stage_gi(gi + 1, wbuf[(gi + 1) & 1], pw, tid);
    const ushort_t* buf = wbuf[gi & 1];
#pragma unroll
    for (int m = 0; m < 4; ++m) {
      acc[qq * 4 + m][0] = (float4v){0.f, 0.f, 0.f, 0.f};
      acc[qq * 4 + m][1] = (float4v){0.f, 0.f, 0.f, 0.f};
    }
    short8 aL[2], aH[2];
    aL[0] = *(const short8*)&buf[((size_t)(0 * KT + 0) * 64 + lane) * 8];
    aL[1] = *(const short8*)&buf[((size_t)(1 * KT + 0) * 64 + lane) * 8];
#pragma unroll
    for (int kt = 0; kt < KT; ++kt) {
      aH[0] = *(const short8*)&buf[((size_t)(2 * KT + kt) * 64 + lane) * 8];
      aH[1] = *(const short8*)&buf[((size_t)(3 * KT + kt) * 64 + lane) * 8];
      short8 b0 = __builtin_bit_cast(short8, hu[kt][0]);
      short8 b1 = __builtin_bit_cast(short8, hu[kt][1]);
      acc[qq * 4 + 0][0] = __builtin_amdgcn_mfma_f32_16x16x32_bf16(aL[0], b0, acc[qq * 4 + 0][0], 0, 0, 0);
      acc[qq * 4 + 0][1] = __builtin_amdgcn_mfma_f32_16x16x32_bf16(aL[0], b1, acc[qq * 4 + 0][1], 0, 0, 0);
      acc[qq * 4 + 1][0] = __builtin_amdgcn_mfma_f32_16x16x32_bf16(aL[1], b0, acc[qq * 4 + 1][0], 0, 0, 0);
      acc[qq * 4 + 1][1] = __builtin_amdgcn_mfma_f32_16x16x32_bf16(aL[1], b1, acc[qq * 4 + 1][1], 0, 0, 0);
      if (kt + 1 < KT) {
        aL[0] = *(const short8*)&buf[((size_t)(0 * KT + kt + 1) * 64 + lane) * 8];
        aL[1] = *(const short8*)&buf[((size_t)(1 * KT + kt + 1) * 64 + lane) * 8];
      }
      acc[qq * 4 + 2][0] = __builtin_amdgcn_mfma_f32_16x16x32_bf16(aH[0], b0, acc[qq * 4 + 2][0], 0, 0, 0);
      acc[qq * 4 + 2][1] = __builtin_amdgcn_mfma_f32_16x16x32_bf16(aH[0], b1, acc[qq * 4 + 2][1], 0, 0, 0);
      acc[qq * 4 + 3][0] = __builtin_amdgcn_mfma_f32_16x16x32_bf16(aH[1], b0, acc[qq * 4 + 3][0], 0, 0, 0);
      acc[qq * 4 + 3][1] = __builtin_amdgcn_mfma_f32_16x16x32_bf16(aH[1], b1, acc[qq * 4 + 3][1], 0, 0, 0);
    }
    __syncthreads();
  }
}

// acc -> bias+relu+bf16 pack -> hu (B operand of next layer, sigma order)
__device__ __forceinline__ void convert_layer(float4v (&acc)[16][2], uint4v (&hu)[8][2],
                                              const float* bwl, int q)
{
#pragma unroll
  for (int mt = 0; mt < 16; ++mt) {
    float4 b4 = *(const float4*)&bwl[mt * 16 + 4 * q];
#pragma unroll
    for (int g = 0; g < 2; ++g) {
      float v0 = fmaxf(acc[mt][g][0] + b4.x, 0.f);
      float v1 = fmaxf(acc[mt][g][1] + b4.y, 0.f);
      float v2 = fmaxf(acc[mt][g][2] + b4.z, 0.f);
      float v3 = fmaxf(acc[mt][g][3] + b4.w, 0.f);
      hu[mt >> 1][g][(mt & 1) * 2 + 0] = pack2(v0, v1);
      hu[mt >> 1][g][(mt & 1) * 2 + 1] = pack2(v2, v3);
    }
  }
}

// ---------------------------------------------------------------------------
// Fused kernel. 256 threads = 4 waves (wave owns 32 points); TWO independent
// blocks per CU so barriers/convert of one block overlap compute of the other.
// Activations in registers; weights stream through 2x32KB LDS quarter buffers.
// ---------------------------------------------------------------------------
template <typename TI>
__global__ __launch_bounds__(256, 2) void lisa_fused_t(
    const TI* __restrict__ coord, const TI* __restrict__ latent,
    const TI* __restrict__ bias0, const TI* __restrict__ bias1,
    const TI* __restrict__ bias2, const TI* __restrict__ bias3,
    const TI* __restrict__ W4,    const TI* __restrict__ b4,
    const ushort_t* __restrict__ pw, TI* __restrict__ out,
    const int* __restrict__ flag, int want)
{
  if (*flag != want) return;
  __shared__ __align__(16) ushort_t wbuf[2][16384];      // 2 x 32 KB quarters
  __shared__ __align__(16) float bw[4 * 256 + 256 + 1];  // biases | w4 | b4

  const int tid  = threadIdx.x;
  const int lane = tid & 63, q = lane >> 4, m15 = lane & 15;
  const int wv   = tid >> 6;                              // 0..3
  const long pbase = (long)blockIdx.x * 128 + wv * 32 + m15;  // group g adds 16

  // ---- stage L0 quarter 0 (async) + bias/w4 table ----
  stage_gi(0, wbuf[0], pw, tid);
  for (int i = tid; i < 1281; i += 256) {
    float v;
    if (i < 256)       v = ldv(bias0, i);
    else if (i < 512)  v = ldv(bias1, i - 256);
    else if (i < 768)  v = ldv(bias2, i - 512);
    else if (i < 1024) v = ldv(bias3, i - 768);
    else if (i < 1280) v = ldv(W4, i - 1024);
    else               v = ldv(b4, 0);
    bw[i] = v;
  }

  // ---- feature build directly into sigma-ordered B-frags (registers) ----
  uint4v hu[8][2];
#pragma unroll
  for (int g = 0; g < 2; ++g) {
    long p = pbase + g * 16;
    float c   = ldv(coord, p);
    float ixv = c * 2048.0f - 0.5f;
    float x0f = floorf(ixv);
    float t   = ixv - x0f;
    int   x0  = (int)x0f;
    int   i0  = imin(imax(x0, 0), NLAT - 1);
    int   i1  = imin(imax(x0 + 1, 0), NLAT - 1);
    float w0 = 1.0f - t, w1 = t;
    int rows0[3] = { imax(i0 - 1, 0), i0, imin(i0 + 1, NLAT - 1) };
    int rows1[3] = { imax(i1 - 1, 0), i1, imin(i1 + 1, NLAT - 1) };
    const TI* lat = latent + (size_t)(p >> 15) * (NLAT * DLAT);
#pragma unroll
    for (int tb = 0; tb < 12; ++tb) {
      int region = tb >> 2;
      int d0 = 16 * (tb & 3) + 4 * q;
      float4 a = load4f(lat + (long)rows0[region] * DLAT + d0);
      float4 b = load4f(lat + (long)rows1[region] * DLAT + d0);
      hu[tb >> 1][g][(tb & 1) * 2 + 0] = pack2(w0 * a.x + w1 * b.x, w0 * a.y + w1 * b.y);
      hu[tb >> 1][g][(tb & 1) * 2 + 1] = pack2(w0 * a.z + w1 * b.z, w0 * a.w + w1 * b.w);
    }
    float pv[4];
#pragma unroll
    for (int s = 0; s < 4; ++s) {
      int f = 192 + 4 * q + s;
      float v = 0.0f;
      if (f == 192) v = c;
      else if (f <= 204) {
        int i = f - 193;
        float fr = (float)(1 << (i >> 1));
        float ang = c * fr;
        v = (i & 1) ? __cosf(ang) : __sinf(ang);
      }
      pv[s] = v;
    }
    hu[6][g][0] = pack2(pv[0], pv[1]);
    hu[6][g][1] = pack2(pv[2], pv[3]);
    hu[6][g][2] = 0; hu[6][g][3] = 0;
  }
  __syncthreads();   // quarter 0 ready (vmcnt drained at barrier), table ready

  float4v acc[16][2];

  run_layer<7>( 0, acc, hu, wbuf, pw, tid, lane);
  convert_layer(acc, hu, bw + 0 * 256, q);
  run_layer<8>( 4, acc, hu, wbuf, pw, tid, lane);
  convert_layer(acc, hu, bw + 1 * 256, q);
  run_layer<8>( 8, acc, hu, wbuf, pw, tid, lane);
  convert_layer(acc, hu, bw + 2 * 256, q);
  run_layer<8>(12, acc, hu, wbuf, pw, tid, lane);

  // ---- final: bias3+relu fused with 256->1 dot against w4 ----
  float partial0 = 0.f, partial1 = 0.f;
#pragma unroll
  for (int mt = 0; mt < 16; ++mt) {
    float4 b3v = *(const float4*)&bw[3 * 256 + mt * 16 + 4 * q];
    float4 w4v = *(const float4*)&bw[1024 + mt * 16 + 4 * q];
    float v;
    v = fmaxf(acc[mt][0][0] + b3v.x, 0.f); partial0 += v * w4v.x;
    v = fmaxf(acc[mt][0][1] + b3v.y, 0.f); partial0 += v * w4v.y;
    v = fmaxf(acc[mt][0][2] + b3v.z, 0.f); partial0 += v * w4v.z;
    v = fmaxf(acc[mt][0][3] + b3v.w, 0.f); partial0 += v * w4v.w;
    v = fmaxf(acc[mt][1][0] + b3v.x, 0.f); partial1 += v * w4v.x;
    v = fmaxf(acc[mt][1][1] + b3v.y, 0.f); partial1 += v * w4v.y;
    v = fmaxf(acc[mt][1][2] + b3v.z, 0.f); partial1 += v * w4v.z;
    v = fmaxf(acc[mt][1][3] + b3v.w, 0.f); partial1 += v * w4v.w;
  }
  partial0 += __shfl_xor(partial0, 16, 64);
  partial0 += __shfl_xor(partial0, 32, 64);
  partial1 += __shfl_xor(partial1, 16, 64);
  partial1 += __shfl_xor(partial1, 32, 64);
  if (lane < 16) {
    float bb = bw[1280];
    stv(out, pbase,      partial0 + bb);
    stv(out, pbase + 16, partial1 + bb);
  }
}

extern "C" void kernel_launch(void* const* d_in, const int* in_sizes, int n_in,
                              void* d_out, int out_size, void* d_ws, size_t ws_size,
                              hipStream_t stream) {
  int* flag = (int*)d_ws;
  ushort_t* pw = (ushort_t*)d_ws + PW_BASE;

  detect_mode<<<1, 64, 0, stream>>>((const ushort_t*)d_in[1], flag);

  // fp32-input variant (flag==1)
  pack_w_t<float><<<62, 512, 0, stream>>>(
      (const float*)d_in[2], (const float*)d_in[4], (const float*)d_in[6],
      (const float*)d_in[8], pw, flag, 1);
  lisa_fused_t<float><<<2048, 256, 0, stream>>>(
      (const float*)d_in[0], (const float*)d_in[1],
      (const float*)d_in[3], (const float*)d_in[5], (const float*)d_in[7],
      (const float*)d_in[9], (const float*)d_in[10], (const float*)d_in[11],
      pw, (float*)d_out, flag, 1);

  // bf16-input variant (flag==0)
  pack_w_t<ushort_t><<<62, 512, 0, stream>>>(
      (const ushort_t*)d_in[2], (const ushort_t*)d_in[4], (const ushort_t*)d_in[6],
      (const ushort_t*)d_in[8], pw, flag, 0);
  lisa_fused_t<ushort_t><<<2048, 256, 0, stream>>>(
      (const ushort_t*)d_in[0], (const ushort_t*)d_in[1],
      (const ushort_t*)d_in[3], (const ushort_t*)d_in[5], (const ushort_t*)d_in[7],
      (const ushort_t*)d_in[9], (const ushort_t*)d_in[10], (const ushort_t*)d_in[11],
      pw, (ushort_t*)d_out, flag, 0);
}